// Round 14
// baseline (696.815 us; speedup 1.0000x reference)
//
#include <hip/hip_runtime.h>
#include <hip/hip_bf16.h>
#include <math.h>

// Problem constants (match reference)
#define N_NODES 50000
#define N_EDGES 800000
#define DIN     64
#define HID     128
#define HEADS   4
#define NGRAPH  64
#define NCLS    8
#define EPSB    1e-5f
#define SLOPE   0.2f
#define MAXC4   64               // edge-chunk (one lane per edge)
#define FP8S    16.0f            // fp8 encode scale
#define FP8SI   (0.25f / FP8S)   // head-mean * decode scale

#define SCB     256                            // scan block size
#define NSB     ((N_NODES + SCB - 1) / SCB)    // 196 scan blocks

#define MPAD    (N_NODES + 64)   // row padding for 64-row GEMM tiles
#define TPAD    136              // LDS tile row pad (128+8)

typedef __hip_bfloat16 bf16;
typedef __attribute__((ext_vector_type(8))) short short8;
typedef __attribute__((ext_vector_type(4))) float f32x4;
typedef __attribute__((ext_vector_type(2))) float f32x2;

__device__ __forceinline__ float b2f(bf16 v) { return __bfloat162float(v); }
__device__ __forceinline__ bf16  f2b(float v) { return __float2bfloat16(v); }
__device__ __forceinline__ float lo_f(unsigned v) {
    unsigned u = v << 16; return __builtin_bit_cast(float, u);
}
__device__ __forceinline__ float hi_f(unsigned v) {
    unsigned u = v & 0xffff0000u; return __builtin_bit_cast(float, u);
}
__device__ __forceinline__ unsigned packbf(float lo, float hi) {
    unsigned l = (unsigned)__builtin_bit_cast(unsigned short, __float2bfloat16(lo));
    unsigned h = (unsigned)__builtin_bit_cast(unsigned short, __float2bfloat16(hi));
    return (h << 16) | l;
}

// ---------------- mega-prep: weights->bf16^T | x->bf16 | degree count | graph bounds ----------------
#define PREP_W  229376
#define PREP_X  (N_NODES * DIN)
#define PREP_T  (PREP_W + PREP_X + N_EDGES)
__global__ void k_prep(const float* __restrict__ s0Wl, const float* __restrict__ s0Wr,
                       const float* __restrict__ s1Wl, const float* __restrict__ s1Wr,
                       const float* __restrict__ g0W,  const float* __restrict__ g1W,
                       const float* __restrict__ idpW, const float* __restrict__ x,
                       const int* __restrict__ ei,     const int* __restrict__ batch,
                       bf16* __restrict__ s0t, bf16* __restrict__ s1t,
                       bf16* __restrict__ g0t, bf16* __restrict__ g1t,
                       bf16* __restrict__ idpt, bf16* __restrict__ xbf,
                       int* __restrict__ deg, int* __restrict__ gstart) {
    int t = blockIdx.x * 256 + threadIdx.x;
    if (t < 16384) { int n = t >> 7, k = t & 127;
        s0t[t] = f2b(k < 64 ? s0Wl[k * 128 + n] : s0Wr[(k - 64) * 128 + n]); return; }
    t -= 16384;
    if (t < 32768) { int n = t >> 8, k = t & 255;
        s1t[t] = f2b(k < 128 ? s1Wl[k * 128 + n] : s1Wr[(k - 128) * 128 + n]); return; }
    t -= 32768;
    if (t < 65536) { int n = t >> 7, k = t & 127; g0t[t] = f2b(g0W[k * 512 + n]); return; }
    t -= 65536;
    if (t < 65536) { int n = t >> 7, k = t & 127; g1t[t] = f2b(g1W[k * 512 + n]); return; }
    t -= 65536;
    if (t < 49152) { int l = t >> 14, r = t & 16383; int n = r >> 7, k = r & 127;
        idpt[t] = f2b(idpW[l * 16384 + k * 128 + n]); return; }
    t -= 49152;
    if (t < PREP_X) { xbf[t] = f2b(x[t]); return; }
    t -= PREP_X;
    if (t < N_EDGES) {
        atomicAdd(&deg[ei[N_EDGES + t]], 1);
        int i = t;
        if (i < N_NODES) {
            int b = batch[i];
            int prev = (i == 0) ? -1 : batch[i - 1];
            for (int g = prev + 1; g <= b; ++g) gstart[g] = i;
            if (i == N_NODES - 1)
                for (int g = b + 1; g <= NGRAPH; ++g) gstart[g] = N_NODES;
        }
    }
}

// hierarchical scan
__global__ void k_scan1(const int* __restrict__ deg, int* __restrict__ row_off,
                        int* __restrict__ bsum) {
    __shared__ int sm[SCB];
    int b = blockIdx.x, t = threadIdx.x;
    int i = b * SCB + t;
    int v = (i < N_NODES) ? deg[i] : 0;
    sm[t] = v;
    __syncthreads();
    for (int off = 1; off < SCB; off <<= 1) {
        int x = (t >= off) ? sm[t - off] : 0;
        __syncthreads();
        sm[t] += x;
        __syncthreads();
    }
    if (i < N_NODES) row_off[i + 1] = sm[t];
    if (t == SCB - 1) bsum[b] = sm[t];
}

__global__ void k_scan2(const int* __restrict__ bsum, int* __restrict__ boff) {
    __shared__ int sm[SCB];
    int t = threadIdx.x;
    int v = (t < NSB) ? bsum[t] : 0;
    sm[t] = v;
    __syncthreads();
    for (int off = 1; off < SCB; off <<= 1) {
        int x = (t >= off) ? sm[t - off] : 0;
        __syncthreads();
        sm[t] += x;
        __syncthreads();
    }
    boff[t] = sm[t] - v;   // exclusive
}

__global__ void k_scan3(int* __restrict__ row_off, const int* __restrict__ boff) {
    int i = blockIdx.x * 256 + threadIdx.x;
    if (i == 0) row_off[0] = 0;
    if (i < N_NODES) row_off[i + 1] += boff[i >> 8];
}

__global__ void k_fill(const int* __restrict__ ei, const int* __restrict__ row_off,
                       int* __restrict__ cursor, int* __restrict__ col) {
    int e = blockIdx.x * 256 + threadIdx.x;
    if (e < N_EDGES) {
        int s = ei[e], d = ei[N_EDGES + e];
        int pos = atomicAdd(&cursor[d], 1);
        col[row_off[d] + pos] = s;
    }
}

// ---------------- SAGE 0 aggregate: bf16 x gathers (128 B rows), 32-bit offsets ----------------
__global__ __launch_bounds__(256) void k_sage_agg0(
        const bf16* __restrict__ xbf, const float* __restrict__ x,
        const int* __restrict__ row_off, const int* __restrict__ col,
        bf16* __restrict__ acat) {
    __shared__ int sCol[4][MAXC4];
    int w = threadIdx.x >> 6, lane = threadIdx.x & 63;
    int i = blockIdx.x * 4 + w;
    int s0 = row_off[i], s1 = row_off[i + 1];
    const char* xs = (const char*)xbf;           // row = 128 bytes
    unsigned loff = (unsigned)lane << 1;
    float acc = 0.f;
    for (int c0 = s0; c0 < s1; c0 += MAXC4) {
        int cnt = min(MAXC4, s1 - c0);
        if (lane < cnt) sCol[w][lane] = col[c0 + lane];
        for (int e = 0; e < cnt; ++e) {
            unsigned off = ((unsigned)sCol[w][e] << 7) | loff;
            acc += lo_f((unsigned)*(const unsigned short*)(xs + off));
        }
    }
    acat[(size_t)i * (2 * DIN) + lane]       = f2b(acc / fmaxf((float)(s1 - s0), 1.0f));
    acat[(size_t)i * (2 * DIN) + DIN + lane] = f2b(x[(size_t)i * DIN + lane]);
}

// ---------------- SAGE 1 aggregate: fp8 hA shadow gathers (128 B rows), 32-bit offsets ----------------
__global__ __launch_bounds__(256) void k_sage_agg1(
        const unsigned char* __restrict__ hA8, const bf16* __restrict__ hA,
        const int* __restrict__ row_off, const int* __restrict__ col,
        bf16* __restrict__ acat) {
    __shared__ int sCol[4][MAXC4];
    int w = threadIdx.x >> 6, lane = threadIdx.x & 63;
    int i = blockIdx.x * 4 + w;
    int s0 = row_off[i], s1 = row_off[i + 1];
    const char* h8 = (const char*)hA8;           // row = 128 bytes (2 fp8/lane)
    unsigned loff = (unsigned)lane << 1;
    f32x2 acc = {0.f, 0.f};
    for (int c0 = s0; c0 < s1; c0 += MAXC4) {
        int cnt = min(MAXC4, s1 - c0);
        if (lane < cnt) sCol[w][lane] = col[c0 + lane];
        for (int e = 0; e < cnt; ++e) {
            unsigned off = ((unsigned)sCol[w][e] << 7) | loff;
            f32x2 p = __builtin_amdgcn_cvt_pk_f32_fp8(
                (int)(unsigned)*(const unsigned short*)(h8 + off), false);
            acc += p;
        }
    }
    float inv = 1.0f / (fmaxf((float)(s1 - s0), 1.0f) * FP8S);
    unsigned* ao = (unsigned*)acat;              // row stride 128 uints
    ao[(size_t)i * HID + lane]             = packbf(acc.x * inv, acc.y * inv);
    ao[(size_t)i * HID + (HID / 2) + lane] = ((const unsigned*)hA)[(size_t)i * (HID / 2) + lane];
}

// ---------------- MFMA GEMM: C = A @ Bt^T, fused epilogue ----------------
// EPI: 1=bias+BN+PReLU (bf16)  5=EPI1 + fp8 shadow  4=fp8-store + GAT scores (head=blockIdx.y)
template <int K, int NT, int EPI>
__global__ __launch_bounds__(256) void k_gemm(
        const bf16* __restrict__ A, const bf16* __restrict__ Bt, void* __restrict__ Cp,
        unsigned char* __restrict__ C8s, int M, int Nc,
        const float* __restrict__ bias, const float* __restrict__ bng,
        const float* __restrict__ bnb,  const float* __restrict__ bnm,
        const float* __restrict__ bnv,  const float* __restrict__ pa,
        const float* __restrict__ asrc, const float* __restrict__ adst,
        float* __restrict__ es, float* __restrict__ ed) {
    int wave = threadIdx.x >> 6, lane = threadIdx.x & 63;
    int ln = lane & 15, q = lane >> 4;
    int m0 = blockIdx.x * 64 + wave * 16;
    int n0 = blockIdx.y * (NT * 16);
    const bf16* arow = A + (size_t)(m0 + ln) * K + q * 8;

    f32x4 acc[NT];
#pragma unroll
    for (int t = 0; t < NT; ++t) acc[t] = (f32x4){0.f, 0.f, 0.f, 0.f};

#pragma unroll
    for (int k = 0; k < K; k += 32) {
        short8 a = *(const short8*)(const void*)(arow + k);
#pragma unroll
        for (int t = 0; t < NT; ++t) {
            short8 b = *(const short8*)(const void*)(Bt + (size_t)(n0 + t * 16 + ln) * K + k + q * 8);
            acc[t] = __builtin_amdgcn_mfma_f32_16x16x32_bf16(a, b, acc[t], 0, 0, 0);
        }
    }

    if (EPI != 4) {
        bf16* C = (bf16*)Cp;
#pragma unroll
        for (int t = 0; t < NT; ++t) {
            int cidx = n0 + t * 16 + ln;
            float bi = bias[cidx];
            float g = bng[cidx], bb = bnb[cidx], mm = bnm[cidx];
            float iv = rsqrtf(bnv[cidx] + EPSB), al = pa[cidx];
#pragma unroll
            for (int r = 0; r < 4; ++r) {
                int mr = m0 + q * 4 + r;
                if (mr < M) {
                    float v = acc[t][r] + bi;
                    v = (v - mm) * iv * g + bb;
                    v = v >= 0.f ? v : al * v;
                    C[(size_t)mr * Nc + cidx] = f2b(v);
                    if (EPI == 5) {
                        int enc = __builtin_amdgcn_cvt_pk_fp8_f32(v * FP8S, 0.f, 0, false);
                        C8s[(size_t)mr * HID + cidx] = (unsigned char)(enc & 0xff);
                    }
                }
            }
        }
    } else {
        // fp8 store (scale FP8S), logical col order
        unsigned char* C8 = (unsigned char*)Cp;
#pragma unroll
        for (int t = 0; t < NT; ++t) {
            int cidx = n0 + t * 16 + ln;
#pragma unroll
            for (int r = 0; r < 4; ++r) {
                int mr = m0 + q * 4 + r;
                if (mr < M) {
                    int enc = __builtin_amdgcn_cvt_pk_fp8_f32(acc[t][r] * FP8S, 0.f, 0, false);
                    C8[(size_t)mr * 512 + cidx] = (unsigned char)(enc & 0xff);
                }
            }
        }
        // GAT scores from fp32 acc
        int head = blockIdx.y;
        float asv[NT], adv[NT];
#pragma unroll
        for (int t = 0; t < NT; ++t) {
            asv[t] = asrc[head * HID + t * 16 + ln];
            adv[t] = adst[head * HID + t * 16 + ln];
        }
#pragma unroll
        for (int r = 0; r < 4; ++r) {
            float ps = 0.f, pd = 0.f;
#pragma unroll
            for (int t = 0; t < NT; ++t) { ps += acc[t][r] * asv[t]; pd += acc[t][r] * adv[t]; }
#pragma unroll
            for (int off = 1; off < 16; off <<= 1) {
                ps += __shfl_xor(ps, off, 16);
                pd += __shfl_xor(pd, off, 16);
            }
            int mr = m0 + q * 4 + r;
            if (ln == 0 && mr < M) {
                es[mr * HEADS + head] = ps;
                ed[mr * HEADS + head] = pd;
            }
        }
    }
}

// ---------------- fused 3-layer IDP MLP (wave-private LDS transpose) ----------------
__global__ __launch_bounds__(256) void k_mlp3(
        const bf16* __restrict__ A,
        const bf16* __restrict__ W0t, const bf16* __restrict__ W1t,
        const bf16* __restrict__ W2t,
        const float* __restrict__ b0, const float* __restrict__ a0,
        const float* __restrict__ b1, const float* __restrict__ a1,
        const float* __restrict__ b2,
        bf16* __restrict__ outp, int M) {
    __shared__ bf16 tile[4][16][TPAD];
    int wave = threadIdx.x >> 6, lane = threadIdx.x & 63;
    int ln = lane & 15, q = lane >> 4;
    int m0 = blockIdx.x * 64 + wave * 16;
    bf16* myt = &tile[wave][0][0];

    f32x4 acc[8];
#pragma unroll
    for (int t = 0; t < 8; ++t) acc[t] = (f32x4){0.f, 0.f, 0.f, 0.f};
    {
        const bf16* arow = A + (size_t)(m0 + ln) * HID + q * 8;
#pragma unroll
        for (int k = 0; k < HID; k += 32) {
            short8 a = *(const short8*)(const void*)(arow + k);
#pragma unroll
            for (int t = 0; t < 8; ++t) {
                short8 b = *(const short8*)(const void*)(W0t + (size_t)(t * 16 + ln) * HID + k + q * 8);
                acc[t] = __builtin_amdgcn_mfma_f32_16x16x32_bf16(a, b, acc[t], 0, 0, 0);
            }
        }
#pragma unroll
        for (int t = 0; t < 8; ++t) {
            int c = t * 16 + ln;
            float bi = b0[c], al = a0[c];
#pragma unroll
            for (int r = 0; r < 4; ++r) {
                float v = acc[t][r] + bi;
                v = v >= 0.f ? v : al * v;
                myt[(q * 4 + r) * TPAD + c] = f2b(v);
            }
        }
    }
    {
#pragma unroll
        for (int t = 0; t < 8; ++t) acc[t] = (f32x4){0.f, 0.f, 0.f, 0.f};
#pragma unroll
        for (int k = 0; k < HID; k += 32) {
            short8 a = *(const short8*)(const void*)(&myt[ln * TPAD + k + q * 8]);
#pragma unroll
            for (int t = 0; t < 8; ++t) {
                short8 b = *(const short8*)(const void*)(W1t + (size_t)(t * 16 + ln) * HID + k + q * 8);
                acc[t] = __builtin_amdgcn_mfma_f32_16x16x32_bf16(a, b, acc[t], 0, 0, 0);
            }
        }
#pragma unroll
        for (int t = 0; t < 8; ++t) {
            int c = t * 16 + ln;
            float bi = b1[c], al = a1[c];
#pragma unroll
            for (int r = 0; r < 4; ++r) {
                float v = acc[t][r] + bi;
                v = v >= 0.f ? v : al * v;
                myt[(q * 4 + r) * TPAD + c] = f2b(v);
            }
        }
    }
    {
#pragma unroll
        for (int t = 0; t < 8; ++t) acc[t] = (f32x4){0.f, 0.f, 0.f, 0.f};
#pragma unroll
        for (int k = 0; k < HID; k += 32) {
            short8 a = *(const short8*)(const void*)(&myt[ln * TPAD + k + q * 8]);
#pragma unroll
            for (int t = 0; t < 8; ++t) {
                short8 b = *(const short8*)(const void*)(W2t + (size_t)(t * 16 + ln) * HID + k + q * 8);
                acc[t] = __builtin_amdgcn_mfma_f32_16x16x32_bf16(a, b, acc[t], 0, 0, 0);
            }
        }
#pragma unroll
        for (int t = 0; t < 8; ++t) {
            int c = t * 16 + ln;
            float bi = b2[c];
#pragma unroll
            for (int r = 0; r < 4; ++r) {
                int mr = m0 + q * 4 + r;
                if (mr < M) outp[(size_t)mr * HID + c] = f2b(acc[t][r] + bi);
            }
        }
    }
}

// ---------------- GAT aggregation: fp8 xw rows (512 B), wave = node, 32-bit offsets ----------------
__global__ __launch_bounds__(256) void k_gat_agg(
        const unsigned char* __restrict__ xw8, const float* __restrict__ es,
        const float* __restrict__ ed, const int* __restrict__ row_off,
        const int* __restrict__ col, const float* __restrict__ bias,
        const float* __restrict__ bng, const float* __restrict__ bnb,
        const float* __restrict__ bnm, const float* __restrict__ bnv,
        const float* __restrict__ pa,
        bf16* __restrict__ out) {
    __shared__ __align__(16) float sEx[4][MAXC4][HEADS];
    __shared__ int sCol[4][MAXC4];
    int w = threadIdx.x >> 6;
    int lane = threadIdx.x & 63;
    int i = blockIdx.x * 4 + w;          // grid = N/4 exactly
    int h = lane >> 4;
    const char* esb = (const char*)es;        // node stride 16 bytes
    unsigned loff = (unsigned)lane << 3;      // lane byte offset within 512 B row
    float4 edi = ((const float4*)ed)[i];

    int s0 = row_off[i], s1 = row_off[i + 1];
    float den0 = 0.f, den1 = 0.f, den2 = 0.f, den3 = 0.f;
    f32x2 a01 = {0.f, 0.f}, a23 = {0.f, 0.f}, a45 = {0.f, 0.f}, a67 = {0.f, 0.f};

    {   // self loop
        float4 ev = *(const float4*)(esb + ((unsigned)i << 4));
        float e0 = ev.x + edi.x; e0 = e0 >= 0.f ? e0 : SLOPE * e0; float x0 = expf(e0);
        float e1 = ev.y + edi.y; e1 = e1 >= 0.f ? e1 : SLOPE * e1; float x1 = expf(e1);
        float e2 = ev.z + edi.z; e2 = e2 >= 0.f ? e2 : SLOPE * e2; float x2 = expf(e2);
        float e3 = ev.w + edi.w; e3 = e3 >= 0.f ? e3 : SLOPE * e3; float x3 = expf(e3);
        if (lane == 0) { den0 = x0; den1 = x1; den2 = x2; den3 = x3; }
        float ex = h == 0 ? x0 : h == 1 ? x1 : h == 2 ? x2 : x3;
        f32x2 ex2 = {ex, ex};
        uint2 v = *(const uint2*)(xw8 + (((unsigned)i << 9) | loff));
        a01 = __builtin_elementwise_fma(__builtin_amdgcn_cvt_pk_f32_fp8((int)v.x, false), ex2, a01);
        a23 = __builtin_elementwise_fma(__builtin_amdgcn_cvt_pk_f32_fp8((int)v.x, true),  ex2, a23);
        a45 = __builtin_elementwise_fma(__builtin_amdgcn_cvt_pk_f32_fp8((int)v.y, false), ex2, a45);
        a67 = __builtin_elementwise_fma(__builtin_amdgcn_cvt_pk_f32_fp8((int)v.y, true),  ex2, a67);
    }
    for (int c0 = s0; c0 < s1; c0 += MAXC4) {
        int cnt = min(MAXC4, s1 - c0);
        // phase A: per-edge exp scores (one lane per edge)
        if (lane < cnt) {
            int sn = col[c0 + lane];
            float4 ev = *(const float4*)(esb + ((unsigned)sn << 4));
            float e0 = ev.x + edi.x; e0 = e0 >= 0.f ? e0 : SLOPE * e0; float x0 = expf(e0);
            float e1 = ev.y + edi.y; e1 = e1 >= 0.f ? e1 : SLOPE * e1; float x1 = expf(e1);
            float e2 = ev.z + edi.z; e2 = e2 >= 0.f ? e2 : SLOPE * e2; float x2 = expf(e2);
            float e3 = ev.w + edi.w; e3 = e3 >= 0.f ? e3 : SLOPE * e3; float x3 = expf(e3);
            den0 += x0; den1 += x1; den2 += x2; den3 += x3;
            sCol[w][lane] = sn;
            f32x4 xv = {x0, x1, x2, x3};
            *(f32x4*)(&sEx[w][lane][0]) = xv;
        }
        // same-wave LDS write->read: program order, no block barrier needed
        // phase B: simple serial loop (R10 form; pipelining/permute regressed R11/R12)
        for (int e = 0; e < cnt; ++e) {
            float ex = sEx[w][e][h];
            f32x2 ex2 = {ex, ex};
            unsigned off = ((unsigned)sCol[w][e] << 9) | loff;
            uint2 v = *(const uint2*)(xw8 + off);
            a01 = __builtin_elementwise_fma(__builtin_amdgcn_cvt_pk_f32_fp8((int)v.x, false), ex2, a01);
            a23 = __builtin_elementwise_fma(__builtin_amdgcn_cvt_pk_f32_fp8((int)v.x, true),  ex2, a23);
            a45 = __builtin_elementwise_fma(__builtin_amdgcn_cvt_pk_f32_fp8((int)v.y, false), ex2, a45);
            a67 = __builtin_elementwise_fma(__builtin_amdgcn_cvt_pk_f32_fp8((int)v.y, true),  ex2, a67);
        }
    }
    for (int off = 1; off < 64; off <<= 1) {
        den0 += __shfl_xor(den0, off, 64);
        den1 += __shfl_xor(den1, off, 64);
        den2 += __shfl_xor(den2, off, 64);
        den3 += __shfl_xor(den3, off, 64);
    }
    float den = h == 0 ? den0 : h == 1 ? den1 : h == 2 ? den2 : den3;
    float inv = 1.0f / den;
    float m[8] = {a01.x * inv, a01.y * inv, a23.x * inv, a23.y * inv,
                  a45.x * inv, a45.y * inv, a67.x * inv, a67.y * inv};
#pragma unroll
    for (int j = 0; j < 8; ++j) {
        m[j] += __shfl_xor(m[j], 16, 64);
        m[j] += __shfl_xor(m[j], 32, 64);
    }
    if (lane < 16) {
        int cb = lane * 8;
        float r[8];
#pragma unroll
        for (int j = 0; j < 8; ++j) {
            int c = cb + j;
            float v = FP8SI * m[j] + bias[c];   // 0.25 head-mean * 1/16 fp8 scale
            v = (v - bnm[c]) * rsqrtf(bnv[c] + EPSB) * bng[c] + bnb[c];
            float al = pa[c];
            r[j] = v >= 0.f ? v : al * v;
        }
        uint4 o;
        o.x = packbf(r[0], r[1]); o.y = packbf(r[2], r[3]);
        o.z = packbf(r[4], r[5]); o.w = packbf(r[6], r[7]);
        ((uint4*)out)[(size_t)i * 16 + lane] = o;
    }
}

// ---------------- fused pool + classifier: one block per graph, no atomics ----------------
__global__ __launch_bounds__(256) void k_poolcls(
        const bf16* __restrict__ h, const int* __restrict__ gstart,
        const float* __restrict__ W, const float* __restrict__ b,
        float* __restrict__ out) {
    __shared__ float sO[4][HID];
    __shared__ float gemb[HID];
    int g = blockIdx.x;
    int w = threadIdx.x >> 6, lane = threadIdx.x & 63;
    int b0 = gstart[g], b1 = gstart[g + 1];
    const unsigned* hb = (const unsigned*)h;
    float a0 = 0.f, a1 = 0.f;
    for (int r = b0 + w; r < b1; r += 4) {
        unsigned v = hb[(size_t)r * (HID / 2) + lane];
        a0 += lo_f(v); a1 += hi_f(v);
    }
    sO[w][2 * lane]     = a0;
    sO[w][2 * lane + 1] = a1;
    __syncthreads();
    int t = threadIdx.x;
    if (t < HID) {
        float s = sO[0][t] + sO[1][t] + sO[2][t] + sO[3][t];
        gemb[t] = s / fmaxf((float)(b1 - b0), 1.0f);
    }
    __syncthreads();
    if (t < NCLS) {
        float acc = b[t];
        for (int k = 0; k < HID; ++k) acc += gemb[k] * W[k * NCLS + t];
        out[g * NCLS + t] = acc;
    }
}

// ---------------- launch ----------------
extern "C" void kernel_launch(void* const* d_in, const int* in_sizes, int n_in,
                              void* d_out, int out_size, void* d_ws, size_t ws_size,
                              hipStream_t stream) {
    const float* x      = (const float*)d_in[0];
    const int*   ei     = (const int*)d_in[1];
    const int*   batch  = (const int*)d_in[2];
    const float* s0_Wl  = (const float*)d_in[3];
    const float* s0_Wr  = (const float*)d_in[4];
    const float* s0_b   = (const float*)d_in[5];
    const float* s1_Wl  = (const float*)d_in[6];
    const float* s1_Wr  = (const float*)d_in[7];
    const float* s1_b   = (const float*)d_in[8];
    const float* bn_g   = (const float*)d_in[9];
    const float* bn_b   = (const float*)d_in[10];
    const float* bn_m   = (const float*)d_in[11];
    const float* bn_v   = (const float*)d_in[12];
    const float* pre_a  = (const float*)d_in[13];
    const float* g0_W   = (const float*)d_in[14];
    const float* g0_as  = (const float*)d_in[15];
    const float* g0_ad  = (const float*)d_in[16];
    const float* g0_bias= (const float*)d_in[17];
    const float* g1_W   = (const float*)d_in[18];
    const float* g1_as  = (const float*)d_in[19];
    const float* g1_ad  = (const float*)d_in[20];
    const float* g1_bias= (const float*)d_in[21];
    const float* idp_W  = (const float*)d_in[22];
    const float* idp_b  = (const float*)d_in[23];
    const float* idp_a  = (const float*)d_in[24];
    const float* cls_W  = (const float*)d_in[25];
    const float* cls_b  = (const float*)d_in[26];
    float* out = (float*)d_out;

    // workspace carve (256B aligned)
    char* p = (char*)d_ws;
    auto alloc = [&](size_t bytes) -> void* {
        void* r = (void*)p;
        p += (bytes + 255) & ~(size_t)255;
        return r;
    };
    int*   degcur  = (int*)alloc((size_t)2 * N_NODES * 4);   // deg | cursor (one memset)
    int*   deg     = degcur;
    int*   cursor  = degcur + N_NODES;
    int*   row_off = (int*)alloc((size_t)(N_NODES + 1) * 4);
    int*   col     = (int*)alloc((size_t)N_EDGES * 4);
    int*   gstart  = (int*)alloc((size_t)(NGRAPH + 1) * 4);
    int*   bsum    = (int*)alloc((size_t)SCB * 4);
    int*   boff    = (int*)alloc((size_t)SCB * 4);
    float* es      = (float*)alloc((size_t)N_NODES * HEADS * 4);
    float* edv     = (float*)alloc((size_t)N_NODES * HEADS * 4);
    bf16*  hA      = (bf16*)alloc((size_t)MPAD * HID * 2);
    bf16*  hB      = (bf16*)alloc((size_t)MPAD * HID * 2);
    bf16*  xbf     = (bf16*)alloc((size_t)N_NODES * DIN * 2);
    unsigned char* hA8 = (unsigned char*)alloc((size_t)MPAD * HID);
    // union: acat0 (MPAD*128 bf16), acat1 (MPAD*256 bf16 = 512B/row), xw8 (MPAD*512 fp8)
    void*  u       = alloc((size_t)MPAD * 512);
    bf16*  acat0   = (bf16*)u;
    bf16*  acat1   = (bf16*)u;
    unsigned char* xw8 = (unsigned char*)u;
    // bf16 transposed weights
    bf16*  s0t     = (bf16*)alloc((size_t)128 * 128 * 2);
    bf16*  s1t     = (bf16*)alloc((size_t)128 * 256 * 2);
    bf16*  g0t     = (bf16*)alloc((size_t)512 * 128 * 2);
    bf16*  g1t     = (bf16*)alloc((size_t)512 * 128 * 2);
    bf16*  idpt    = (bf16*)alloc((size_t)3 * 128 * 128 * 2);

    hipMemsetAsync(degcur, 0, (size_t)2 * N_NODES * 4, stream);

    // mega-prep: weights, x->bf16, degree count, graph bounds
    k_prep<<<(PREP_T + 255) / 256, 256, 0, stream>>>(
        s0_Wl, s0_Wr, s1_Wl, s1_Wr, g0_W, g1_W, idp_W, x, ei, batch,
        s0t, s1t, g0t, g1t, idpt, xbf, deg, gstart);
    k_scan1<<<NSB, SCB, 0, stream>>>(deg, row_off, bsum);
    k_scan2<<<1, SCB, 0, stream>>>(bsum, boff);
    k_scan3<<<(N_NODES + 255) / 256, 256, 0, stream>>>(row_off, boff);
    k_fill<<<(N_EDGES + 255) / 256, 256, 0, stream>>>(ei, row_off, cursor, col);

    const int MB = (N_NODES + 63) / 64;   // 782 row-blocks

    // SAGE 0 (gemm also writes fp8 shadow hA8 for SAGE1's gathers)
    k_sage_agg0<<<N_NODES / 4, 256, 0, stream>>>(xbf, x, row_off, col, acat0);
    k_gemm<128, 8, 5><<<dim3(MB, 1), 256, 0, stream>>>(
        acat0, s0t, hA, hA8, N_NODES, HID,
        s0_b, bn_g + 0 * HID, bn_b + 0 * HID, bn_m + 0 * HID, bn_v + 0 * HID, pre_a + 0 * HID,
        nullptr, nullptr, nullptr, nullptr);

    // SAGE 1
    k_sage_agg1<<<N_NODES / 4, 256, 0, stream>>>(hA8, hA, row_off, col, acat1);
    k_gemm<256, 8, 1><<<dim3(MB, 1), 256, 0, stream>>>(
        acat1, s1t, hB, nullptr, N_NODES, HID,
        s1_b, bn_g + 1 * HID, bn_b + 1 * HID, bn_m + 1 * HID, bn_v + 1 * HID, pre_a + 1 * HID,
        nullptr, nullptr, nullptr, nullptr);

    // GAT 0 (gemm stores fp8 xw + fuses score computation)
    k_gemm<128, 8, 4><<<dim3(MB, 4), 256, 0, stream>>>(
        hB, g0t, xw8, nullptr, N_NODES, HEADS * HID,
        nullptr, nullptr, nullptr, nullptr, nullptr, nullptr,
        g0_as, g0_ad, es, edv);
    k_gat_agg<<<N_NODES / 4, 256, 0, stream>>>(
        xw8, es, edv, row_off, col, g0_bias,
        bn_g + 2 * HID, bn_b + 2 * HID, bn_m + 2 * HID, bn_v + 2 * HID, pre_a + 2 * HID, hA);

    // GAT 1
    k_gemm<128, 8, 4><<<dim3(MB, 4), 256, 0, stream>>>(
        hA, g1t, xw8, nullptr, N_NODES, HEADS * HID,
        nullptr, nullptr, nullptr, nullptr, nullptr, nullptr,
        g1_as, g1_ad, es, edv);
    k_gat_agg<<<N_NODES / 4, 256, 0, stream>>>(
        xw8, es, edv, row_off, col, g1_bias,
        bn_g + 3 * HID, bn_b + 3 * HID, bn_m + 3 * HID, bn_v + 3 * HID, pre_a + 3 * HID, hB);

    // IDP MLP (3 layers fused)
    k_mlp3<<<MB, 256, 0, stream>>>(
        hB, idpt + 0 * 16384, idpt + 1 * 16384, idpt + 2 * 16384,
        idp_b + 0 * HID, idp_a + 0 * HID,
        idp_b + 1 * HID, idp_a + 1 * HID,
        idp_b + 2 * HID, hA, N_NODES);

    // fused global mean pool + classifier (one block per graph)
    k_poolcls<<<NGRAPH, 256, 0, stream>>>(hA, gstart, cls_W, cls_b, out);
}

// Round 15
// 629.771 us; speedup vs baseline: 1.1065x; 1.1065x over previous
//
#include <hip/hip_runtime.h>
#include <hip/hip_bf16.h>
#include <math.h>

// Problem constants (match reference)
#define N_NODES 50000
#define N_EDGES 800000
#define DIN     64
#define HID     128
#define HEADS   4
#define NGRAPH  64
#define NCLS    8
#define EPSB    1e-5f
#define SLOPE   0.2f
#define MAXC4   64               // edge-chunk (one lane per edge)
#define FP8S    16.0f            // fp8 encode scale
#define FP8SI   (0.25f / FP8S)   // head-mean * decode scale

#define SCB     256                            // scan block size
#define NSB     ((N_NODES + SCB - 1) / SCB)    // 196 scan blocks

#define MPAD    (N_NODES + 64)   // row padding for 64-row GEMM tiles
#define TPAD    136              // LDS tile row pad (128+8)

typedef __hip_bfloat16 bf16;
typedef __attribute__((ext_vector_type(8))) short short8;
typedef __attribute__((ext_vector_type(4))) float f32x4;
typedef __attribute__((ext_vector_type(2))) float f32x2;

__device__ __forceinline__ float b2f(bf16 v) { return __bfloat162float(v); }
__device__ __forceinline__ bf16  f2b(float v) { return __float2bfloat16(v); }
__device__ __forceinline__ float lo_f(unsigned v) {
    unsigned u = v << 16; return __builtin_bit_cast(float, u);
}
__device__ __forceinline__ float hi_f(unsigned v) {
    unsigned u = v & 0xffff0000u; return __builtin_bit_cast(float, u);
}
__device__ __forceinline__ unsigned packbf(float lo, float hi) {
    unsigned l = (unsigned)__builtin_bit_cast(unsigned short, __float2bfloat16(lo));
    unsigned h = (unsigned)__builtin_bit_cast(unsigned short, __float2bfloat16(hi));
    return (h << 16) | l;
}

// ---------------- mega-prep: weights->bf16^T | x->fp8 | degree count | graph bounds ----------------
#define PREP_W  229376
#define PREP_X  (N_NODES * DIN)
#define PREP_T  (PREP_W + PREP_X + N_EDGES)
__global__ void k_prep(const float* __restrict__ s0Wl, const float* __restrict__ s0Wr,
                       const float* __restrict__ s1Wl, const float* __restrict__ s1Wr,
                       const float* __restrict__ g0W,  const float* __restrict__ g1W,
                       const float* __restrict__ idpW, const float* __restrict__ x,
                       const int* __restrict__ ei,     const int* __restrict__ batch,
                       bf16* __restrict__ s0t, bf16* __restrict__ s1t,
                       bf16* __restrict__ g0t, bf16* __restrict__ g1t,
                       bf16* __restrict__ idpt, unsigned char* __restrict__ x8,
                       int* __restrict__ deg, int* __restrict__ gstart) {
    int t = blockIdx.x * 256 + threadIdx.x;
    if (t < 16384) { int n = t >> 7, k = t & 127;
        s0t[t] = f2b(k < 64 ? s0Wl[k * 128 + n] : s0Wr[(k - 64) * 128 + n]); return; }
    t -= 16384;
    if (t < 32768) { int n = t >> 8, k = t & 255;
        s1t[t] = f2b(k < 128 ? s1Wl[k * 128 + n] : s1Wr[(k - 128) * 128 + n]); return; }
    t -= 32768;
    if (t < 65536) { int n = t >> 7, k = t & 127; g0t[t] = f2b(g0W[k * 512 + n]); return; }
    t -= 65536;
    if (t < 65536) { int n = t >> 7, k = t & 127; g1t[t] = f2b(g1W[k * 512 + n]); return; }
    t -= 65536;
    if (t < 49152) { int l = t >> 14, r = t & 16383; int n = r >> 7, k = r & 127;
        idpt[t] = f2b(idpW[l * 16384 + k * 128 + n]); return; }
    t -= 49152;
    if (t < PREP_X) {
        int enc = __builtin_amdgcn_cvt_pk_fp8_f32(x[t] * FP8S, 0.f, 0, false);
        x8[t] = (unsigned char)(enc & 0xff);
        return;
    }
    t -= PREP_X;
    if (t < N_EDGES) {
        atomicAdd(&deg[ei[N_EDGES + t]], 1);
        int i = t;
        if (i < N_NODES) {
            int b = batch[i];
            int prev = (i == 0) ? -1 : batch[i - 1];
            for (int g = prev + 1; g <= b; ++g) gstart[g] = i;
            if (i == N_NODES - 1)
                for (int g = b + 1; g <= NGRAPH; ++g) gstart[g] = N_NODES;
        }
    }
}

// hierarchical scan
__global__ void k_scan1(const int* __restrict__ deg, int* __restrict__ row_off,
                        int* __restrict__ bsum) {
    __shared__ int sm[SCB];
    int b = blockIdx.x, t = threadIdx.x;
    int i = b * SCB + t;
    int v = (i < N_NODES) ? deg[i] : 0;
    sm[t] = v;
    __syncthreads();
    for (int off = 1; off < SCB; off <<= 1) {
        int x = (t >= off) ? sm[t - off] : 0;
        __syncthreads();
        sm[t] += x;
        __syncthreads();
    }
    if (i < N_NODES) row_off[i + 1] = sm[t];
    if (t == SCB - 1) bsum[b] = sm[t];
}

__global__ void k_scan2(const int* __restrict__ bsum, int* __restrict__ boff) {
    __shared__ int sm[SCB];
    int t = threadIdx.x;
    int v = (t < NSB) ? bsum[t] : 0;
    sm[t] = v;
    __syncthreads();
    for (int off = 1; off < SCB; off <<= 1) {
        int x = (t >= off) ? sm[t - off] : 0;
        __syncthreads();
        sm[t] += x;
        __syncthreads();
    }
    boff[t] = sm[t] - v;   // exclusive
}

__global__ void k_scan3(int* __restrict__ row_off, const int* __restrict__ boff) {
    int i = blockIdx.x * 256 + threadIdx.x;
    if (i == 0) row_off[0] = 0;
    if (i < N_NODES) row_off[i + 1] += boff[i >> 8];
}

__global__ void k_fill(const int* __restrict__ ei, const int* __restrict__ row_off,
                       int* __restrict__ cursor, int* __restrict__ col) {
    int e = blockIdx.x * 256 + threadIdx.x;
    if (e < N_EDGES) {
        int s = ei[e], d = ei[N_EDGES + e];
        int pos = atomicAdd(&cursor[d], 1);
        col[row_off[d] + pos] = s;
    }
}

// ---------------- SAGE 0 aggregate: fp8 x gathers (64 B rows), fp32 self ----------------
__global__ __launch_bounds__(256) void k_sage_agg0(
        const unsigned char* __restrict__ x8, const float* __restrict__ x,
        const int* __restrict__ row_off, const int* __restrict__ col,
        bf16* __restrict__ acat) {
    __shared__ int sCol[4][MAXC4];
    int w = threadIdx.x >> 6, lane = threadIdx.x & 63;
    int i = blockIdx.x * 4 + w;
    int s0 = row_off[i], s1 = row_off[i + 1];
    float acc = 0.f;
    for (int c0 = s0; c0 < s1; c0 += MAXC4) {
        int cnt = min(MAXC4, s1 - c0);
        if (lane < cnt) sCol[w][lane] = col[c0 + lane];
        for (int e = 0; e < cnt; ++e) {
            unsigned off = ((unsigned)sCol[w][e] << 6) | (unsigned)lane;
            f32x2 p = __builtin_amdgcn_cvt_pk_f32_fp8((int)(unsigned)x8[off], false);
            acc += p.x;
        }
    }
    float inv = 1.0f / (fmaxf((float)(s1 - s0), 1.0f) * FP8S);
    acat[(size_t)i * (2 * DIN) + lane]       = f2b(acc * inv);
    acat[(size_t)i * (2 * DIN) + DIN + lane] = f2b(x[(size_t)i * DIN + lane]);
}

// ---------------- SAGE 1 aggregate: fp8 hA shadow gathers (128 B rows) ----------------
__global__ __launch_bounds__(256) void k_sage_agg1(
        const unsigned char* __restrict__ hA8, const bf16* __restrict__ hA,
        const int* __restrict__ row_off, const int* __restrict__ col,
        bf16* __restrict__ acat) {
    __shared__ int sCol[4][MAXC4];
    int w = threadIdx.x >> 6, lane = threadIdx.x & 63;
    int i = blockIdx.x * 4 + w;
    int s0 = row_off[i], s1 = row_off[i + 1];
    const char* h8 = (const char*)hA8;           // row = 128 bytes (2 fp8/lane)
    unsigned loff = (unsigned)lane << 1;
    f32x2 acc = {0.f, 0.f};
    for (int c0 = s0; c0 < s1; c0 += MAXC4) {
        int cnt = min(MAXC4, s1 - c0);
        if (lane < cnt) sCol[w][lane] = col[c0 + lane];
        for (int e = 0; e < cnt; ++e) {
            unsigned off = ((unsigned)sCol[w][e] << 7) | loff;
            f32x2 p = __builtin_amdgcn_cvt_pk_f32_fp8(
                (int)(unsigned)*(const unsigned short*)(h8 + off), false);
            acc += p;
        }
    }
    float inv = 1.0f / (fmaxf((float)(s1 - s0), 1.0f) * FP8S);
    unsigned* ao = (unsigned*)acat;              // row stride 128 uints
    ao[(size_t)i * HID + lane]             = packbf(acc.x * inv, acc.y * inv);
    ao[(size_t)i * HID + (HID / 2) + lane] = ((const unsigned*)hA)[(size_t)i * (HID / 2) + lane];
}

// ---------------- MFMA GEMM: C = A @ Bt^T, fused epilogue ----------------
// EPI: 1=bias+BN+PReLU (bf16)  5=EPI1 + fp8 shadow  4=fp8-store + GAT scores (head=blockIdx.y)
template <int K, int NT, int EPI>
__global__ __launch_bounds__(256) void k_gemm(
        const bf16* __restrict__ A, const bf16* __restrict__ Bt, void* __restrict__ Cp,
        unsigned char* __restrict__ C8s, int M, int Nc,
        const float* __restrict__ bias, const float* __restrict__ bng,
        const float* __restrict__ bnb,  const float* __restrict__ bnm,
        const float* __restrict__ bnv,  const float* __restrict__ pa,
        const float* __restrict__ asrc, const float* __restrict__ adst,
        float* __restrict__ es, float* __restrict__ ed) {
    int wave = threadIdx.x >> 6, lane = threadIdx.x & 63;
    int ln = lane & 15, q = lane >> 4;
    int m0 = blockIdx.x * 64 + wave * 16;
    int n0 = blockIdx.y * (NT * 16);
    const bf16* arow = A + (size_t)(m0 + ln) * K + q * 8;

    f32x4 acc[NT];
#pragma unroll
    for (int t = 0; t < NT; ++t) acc[t] = (f32x4){0.f, 0.f, 0.f, 0.f};

#pragma unroll
    for (int k = 0; k < K; k += 32) {
        short8 a = *(const short8*)(const void*)(arow + k);
#pragma unroll
        for (int t = 0; t < NT; ++t) {
            short8 b = *(const short8*)(const void*)(Bt + (size_t)(n0 + t * 16 + ln) * K + k + q * 8);
            acc[t] = __builtin_amdgcn_mfma_f32_16x16x32_bf16(a, b, acc[t], 0, 0, 0);
        }
    }

    if (EPI != 4) {
        bf16* C = (bf16*)Cp;
#pragma unroll
        for (int t = 0; t < NT; ++t) {
            int cidx = n0 + t * 16 + ln;
            float bi = bias[cidx];
            float g = bng[cidx], bb = bnb[cidx], mm = bnm[cidx];
            float iv = rsqrtf(bnv[cidx] + EPSB), al = pa[cidx];
#pragma unroll
            for (int r = 0; r < 4; ++r) {
                int mr = m0 + q * 4 + r;
                if (mr < M) {
                    float v = acc[t][r] + bi;
                    v = (v - mm) * iv * g + bb;
                    v = v >= 0.f ? v : al * v;
                    C[(size_t)mr * Nc + cidx] = f2b(v);
                    if (EPI == 5) {
                        int enc = __builtin_amdgcn_cvt_pk_fp8_f32(v * FP8S, 0.f, 0, false);
                        C8s[(size_t)mr * HID + cidx] = (unsigned char)(enc & 0xff);
                    }
                }
            }
        }
    } else {
        // fp8 store (scale FP8S), logical col order
        unsigned char* C8 = (unsigned char*)Cp;
#pragma unroll
        for (int t = 0; t < NT; ++t) {
            int cidx = n0 + t * 16 + ln;
#pragma unroll
            for (int r = 0; r < 4; ++r) {
                int mr = m0 + q * 4 + r;
                if (mr < M) {
                    int enc = __builtin_amdgcn_cvt_pk_fp8_f32(acc[t][r] * FP8S, 0.f, 0, false);
                    C8[(size_t)mr * 512 + cidx] = (unsigned char)(enc & 0xff);
                }
            }
        }
        // GAT scores from fp32 acc
        int head = blockIdx.y;
        float asv[NT], adv[NT];
#pragma unroll
        for (int t = 0; t < NT; ++t) {
            asv[t] = asrc[head * HID + t * 16 + ln];
            adv[t] = adst[head * HID + t * 16 + ln];
        }
#pragma unroll
        for (int r = 0; r < 4; ++r) {
            float ps = 0.f, pd = 0.f;
#pragma unroll
            for (int t = 0; t < NT; ++t) { ps += acc[t][r] * asv[t]; pd += acc[t][r] * adv[t]; }
#pragma unroll
            for (int off = 1; off < 16; off <<= 1) {
                ps += __shfl_xor(ps, off, 16);
                pd += __shfl_xor(pd, off, 16);
            }
            int mr = m0 + q * 4 + r;
            if (ln == 0 && mr < M) {
                es[mr * HEADS + head] = ps;
                ed[mr * HEADS + head] = pd;
            }
        }
    }
}

// ---------------- fused 3-layer IDP MLP + mean-pool accumulation ----------------
// Output of layer 2 is consumed ONLY by graph mean-pool: never materialized.
// Per-wave LDS tile holds layer outputs; epilogue does per-lane (2 channels)
// segmented sum over the wave's 16 rows (batch sorted => <=2 graph flushes).
__global__ __launch_bounds__(256) void k_mlp3(
        const bf16* __restrict__ A,
        const bf16* __restrict__ W0t, const bf16* __restrict__ W1t,
        const bf16* __restrict__ W2t,
        const float* __restrict__ b0, const float* __restrict__ a0,
        const float* __restrict__ b1, const float* __restrict__ a1,
        const float* __restrict__ b2, const int* __restrict__ batch,
        float* __restrict__ pool, int M) {
    __shared__ bf16 tile[4][16][TPAD];
    __shared__ int sB[4][16];
    int wave = threadIdx.x >> 6, lane = threadIdx.x & 63;
    int ln = lane & 15, q = lane >> 4;
    int m0 = blockIdx.x * 64 + wave * 16;
    bf16* myt = &tile[wave][0][0];
    if (q == 0) sB[wave][ln] = (m0 + ln < M) ? batch[m0 + ln] : -1;

    f32x4 acc[8];
#pragma unroll
    for (int t = 0; t < 8; ++t) acc[t] = (f32x4){0.f, 0.f, 0.f, 0.f};
    {   // layer 0: A from global
        const bf16* arow = A + (size_t)(m0 + ln) * HID + q * 8;
#pragma unroll
        for (int k = 0; k < HID; k += 32) {
            short8 a = *(const short8*)(const void*)(arow + k);
#pragma unroll
            for (int t = 0; t < 8; ++t) {
                short8 b = *(const short8*)(const void*)(W0t + (size_t)(t * 16 + ln) * HID + k + q * 8);
                acc[t] = __builtin_amdgcn_mfma_f32_16x16x32_bf16(a, b, acc[t], 0, 0, 0);
            }
        }
#pragma unroll
        for (int t = 0; t < 8; ++t) {
            int c = t * 16 + ln;
            float bi = b0[c], al = a0[c];
#pragma unroll
            for (int r = 0; r < 4; ++r) {
                float v = acc[t][r] + bi;
                v = v >= 0.f ? v : al * v;
                myt[(q * 4 + r) * TPAD + c] = f2b(v);
            }
        }
    }
    {   // layer 1: A from LDS (same-wave, program order)
#pragma unroll
        for (int t = 0; t < 8; ++t) acc[t] = (f32x4){0.f, 0.f, 0.f, 0.f};
#pragma unroll
        for (int k = 0; k < HID; k += 32) {
            short8 a = *(const short8*)(const void*)(&myt[ln * TPAD + k + q * 8]);
#pragma unroll
            for (int t = 0; t < 8; ++t) {
                short8 b = *(const short8*)(const void*)(W1t + (size_t)(t * 16 + ln) * HID + k + q * 8);
                acc[t] = __builtin_amdgcn_mfma_f32_16x16x32_bf16(a, b, acc[t], 0, 0, 0);
            }
        }
#pragma unroll
        for (int t = 0; t < 8; ++t) {
            int c = t * 16 + ln;
            float bi = b1[c], al = a1[c];
#pragma unroll
            for (int r = 0; r < 4; ++r) {
                float v = acc[t][r] + bi;
                v = v >= 0.f ? v : al * v;
                myt[(q * 4 + r) * TPAD + c] = f2b(v);
            }
        }
    }
    {   // layer 2: bias only -> LDS tile
#pragma unroll
        for (int t = 0; t < 8; ++t) acc[t] = (f32x4){0.f, 0.f, 0.f, 0.f};
#pragma unroll
        for (int k = 0; k < HID; k += 32) {
            short8 a = *(const short8*)(const void*)(&myt[ln * TPAD + k + q * 8]);
#pragma unroll
            for (int t = 0; t < 8; ++t) {
                short8 b = *(const short8*)(const void*)(W2t + (size_t)(t * 16 + ln) * HID + k + q * 8);
                acc[t] = __builtin_amdgcn_mfma_f32_16x16x32_bf16(a, b, acc[t], 0, 0, 0);
            }
        }
#pragma unroll
        for (int t = 0; t < 8; ++t) {
            int c = t * 16 + ln;
            float bi = b2[c];
#pragma unroll
            for (int r = 0; r < 4; ++r)
                myt[(q * 4 + r) * TPAD + c] = f2b(acc[t][r] + bi);
        }
    }
    // segmented mean-pool partials: lane covers channels 2*lane, 2*lane+1
    float pa0 = 0.f, pa1 = 0.f;
    int curg = -1;
    for (int j = 0; j < 16; ++j) {
        int g = sB[wave][j];
        if (g < 0) continue;
        if (g != curg) {
            if (curg >= 0) {
                atomicAdd(&pool[curg * HID + 2 * lane], pa0);
                atomicAdd(&pool[curg * HID + 2 * lane + 1], pa1);
            }
            curg = g; pa0 = 0.f; pa1 = 0.f;
        }
        unsigned v = *(const unsigned*)&myt[j * TPAD + 2 * lane];
        pa0 += lo_f(v); pa1 += hi_f(v);
    }
    if (curg >= 0) {
        atomicAdd(&pool[curg * HID + 2 * lane], pa0);
        atomicAdd(&pool[curg * HID + 2 * lane + 1], pa1);
    }
}

// ---------------- GAT aggregation: fp8 xw rows (512 B), wave = node ----------------
__global__ __launch_bounds__(256) void k_gat_agg(
        const unsigned char* __restrict__ xw8, const float* __restrict__ es,
        const float* __restrict__ ed, const int* __restrict__ row_off,
        const int* __restrict__ col, const float* __restrict__ bias,
        const float* __restrict__ bng, const float* __restrict__ bnb,
        const float* __restrict__ bnm, const float* __restrict__ bnv,
        const float* __restrict__ pa,
        bf16* __restrict__ out) {
    __shared__ __align__(16) float sEx[4][MAXC4][HEADS];
    __shared__ int sCol[4][MAXC4];
    int w = threadIdx.x >> 6;
    int lane = threadIdx.x & 63;
    int i = blockIdx.x * 4 + w;          // grid = N/4 exactly
    int h = lane >> 4;
    const char* esb = (const char*)es;        // node stride 16 bytes
    unsigned loff = (unsigned)lane << 3;      // lane byte offset within 512 B row
    float4 edi = ((const float4*)ed)[i];

    int s0 = row_off[i], s1 = row_off[i + 1];
    float den0 = 0.f, den1 = 0.f, den2 = 0.f, den3 = 0.f;
    f32x2 a01 = {0.f, 0.f}, a23 = {0.f, 0.f}, a45 = {0.f, 0.f}, a67 = {0.f, 0.f};

    {   // self loop
        float4 ev = *(const float4*)(esb + ((unsigned)i << 4));
        float e0 = ev.x + edi.x; e0 = e0 >= 0.f ? e0 : SLOPE * e0; float x0 = expf(e0);
        float e1 = ev.y + edi.y; e1 = e1 >= 0.f ? e1 : SLOPE * e1; float x1 = expf(e1);
        float e2 = ev.z + edi.z; e2 = e2 >= 0.f ? e2 : SLOPE * e2; float x2 = expf(e2);
        float e3 = ev.w + edi.w; e3 = e3 >= 0.f ? e3 : SLOPE * e3; float x3 = expf(e3);
        if (lane == 0) { den0 = x0; den1 = x1; den2 = x2; den3 = x3; }
        float ex = h == 0 ? x0 : h == 1 ? x1 : h == 2 ? x2 : x3;
        f32x2 ex2 = {ex, ex};
        uint2 v = *(const uint2*)(xw8 + (((unsigned)i << 9) | loff));
        a01 = __builtin_elementwise_fma(__builtin_amdgcn_cvt_pk_f32_fp8((int)v.x, false), ex2, a01);
        a23 = __builtin_elementwise_fma(__builtin_amdgcn_cvt_pk_f32_fp8((int)v.x, true),  ex2, a23);
        a45 = __builtin_elementwise_fma(__builtin_amdgcn_cvt_pk_f32_fp8((int)v.y, false), ex2, a45);
        a67 = __builtin_elementwise_fma(__builtin_amdgcn_cvt_pk_f32_fp8((int)v.y, true),  ex2, a67);
    }
    for (int c0 = s0; c0 < s1; c0 += MAXC4) {
        int cnt = min(MAXC4, s1 - c0);
        // phase A: per-edge exp scores (one lane per edge)
        if (lane < cnt) {
            int sn = col[c0 + lane];
            float4 ev = *(const float4*)(esb + ((unsigned)sn << 4));
            float e0 = ev.x + edi.x; e0 = e0 >= 0.f ? e0 : SLOPE * e0; float x0 = expf(e0);
            float e1 = ev.y + edi.y; e1 = e1 >= 0.f ? e1 : SLOPE * e1; float x1 = expf(e1);
            float e2 = ev.z + edi.z; e2 = e2 >= 0.f ? e2 : SLOPE * e2; float x2 = expf(e2);
            float e3 = ev.w + edi.w; e3 = e3 >= 0.f ? e3 : SLOPE * e3; float x3 = expf(e3);
            den0 += x0; den1 += x1; den2 += x2; den3 += x3;
            sCol[w][lane] = sn;
            f32x4 xv = {x0, x1, x2, x3};
            *(f32x4*)(&sEx[w][lane][0]) = xv;
        }
        // same-wave LDS write->read: program order, no block barrier needed
        // phase B: simple serial loop (R10 form; pipelining/permute regressed R11/R12)
        for (int e = 0; e < cnt; ++e) {
            float ex = sEx[w][e][h];
            f32x2 ex2 = {ex, ex};
            unsigned off = ((unsigned)sCol[w][e] << 9) | loff;
            uint2 v = *(const uint2*)(xw8 + off);
            a01 = __builtin_elementwise_fma(__builtin_amdgcn_cvt_pk_f32_fp8((int)v.x, false), ex2, a01);
            a23 = __builtin_elementwise_fma(__builtin_amdgcn_cvt_pk_f32_fp8((int)v.x, true),  ex2, a23);
            a45 = __builtin_elementwise_fma(__builtin_amdgcn_cvt_pk_f32_fp8((int)v.y, false), ex2, a45);
            a67 = __builtin_elementwise_fma(__builtin_amdgcn_cvt_pk_f32_fp8((int)v.y, true),  ex2, a67);
        }
    }
    for (int off = 1; off < 64; off <<= 1) {
        den0 += __shfl_xor(den0, off, 64);
        den1 += __shfl_xor(den1, off, 64);
        den2 += __shfl_xor(den2, off, 64);
        den3 += __shfl_xor(den3, off, 64);
    }
    float den = h == 0 ? den0 : h == 1 ? den1 : h == 2 ? den2 : den3;
    float inv = 1.0f / den;
    float m[8] = {a01.x * inv, a01.y * inv, a23.x * inv, a23.y * inv,
                  a45.x * inv, a45.y * inv, a67.x * inv, a67.y * inv};
#pragma unroll
    for (int j = 0; j < 8; ++j) {
        m[j] += __shfl_xor(m[j], 16, 64);
        m[j] += __shfl_xor(m[j], 32, 64);
    }
    if (lane < 16) {
        int cb = lane * 8;
        float r[8];
#pragma unroll
        for (int j = 0; j < 8; ++j) {
            int c = cb + j;
            float v = FP8SI * m[j] + bias[c];   // 0.25 head-mean * 1/16 fp8 scale
            v = (v - bnm[c]) * rsqrtf(bnv[c] + EPSB) * bng[c] + bnb[c];
            float al = pa[c];
            r[j] = v >= 0.f ? v : al * v;
        }
        uint4 o;
        o.x = packbf(r[0], r[1]); o.y = packbf(r[2], r[3]);
        o.z = packbf(r[4], r[5]); o.w = packbf(r[6], r[7]);
        ((uint4*)out)[(size_t)i * 16 + lane] = o;
    }
}

// ---------------- classifier (pool already accumulated by k_mlp3) ----------------
__global__ void k_cls(const float* __restrict__ pool, const int* __restrict__ gstart,
                      const float* __restrict__ W, const float* __restrict__ b,
                      float* __restrict__ out) {
    int t = threadIdx.x;            // 512 = 64*8
    int g = t / NCLS, n = t % NCLS;
    float ic = 1.0f / fmaxf((float)(gstart[g + 1] - gstart[g]), 1.0f);
    float acc = b[n];
    for (int k = 0; k < HID; ++k)
        acc += pool[g * HID + k] * ic * W[k * NCLS + n];
    out[g * NCLS + n] = acc;
}

// ---------------- launch ----------------
extern "C" void kernel_launch(void* const* d_in, const int* in_sizes, int n_in,
                              void* d_out, int out_size, void* d_ws, size_t ws_size,
                              hipStream_t stream) {
    const float* x      = (const float*)d_in[0];
    const int*   ei     = (const int*)d_in[1];
    const int*   batch  = (const int*)d_in[2];
    const float* s0_Wl  = (const float*)d_in[3];
    const float* s0_Wr  = (const float*)d_in[4];
    const float* s0_b   = (const float*)d_in[5];
    const float* s1_Wl  = (const float*)d_in[6];
    const float* s1_Wr  = (const float*)d_in[7];
    const float* s1_b   = (const float*)d_in[8];
    const float* bn_g   = (const float*)d_in[9];
    const float* bn_b   = (const float*)d_in[10];
    const float* bn_m   = (const float*)d_in[11];
    const float* bn_v   = (const float*)d_in[12];
    const float* pre_a  = (const float*)d_in[13];
    const float* g0_W   = (const float*)d_in[14];
    const float* g0_as  = (const float*)d_in[15];
    const float* g0_ad  = (const float*)d_in[16];
    const float* g0_bias= (const float*)d_in[17];
    const float* g1_W   = (const float*)d_in[18];
    const float* g1_as  = (const float*)d_in[19];
    const float* g1_ad  = (const float*)d_in[20];
    const float* g1_bias= (const float*)d_in[21];
    const float* idp_W  = (const float*)d_in[22];
    const float* idp_b  = (const float*)d_in[23];
    const float* idp_a  = (const float*)d_in[24];
    const float* cls_W  = (const float*)d_in[25];
    const float* cls_b  = (const float*)d_in[26];
    float* out = (float*)d_out;

    // workspace carve (256B aligned)
    char* p = (char*)d_ws;
    auto alloc = [&](size_t bytes) -> void* {
        void* r = (void*)p;
        p += (bytes + 255) & ~(size_t)255;
        return r;
    };
    // zero block: deg | cursor | pool — single memset
    int*   zb      = (int*)alloc((size_t)(2 * N_NODES + NGRAPH * HID) * 4);
    int*   deg     = zb;
    int*   cursor  = zb + N_NODES;
    float* pool    = (float*)(zb + 2 * N_NODES);
    int*   row_off = (int*)alloc((size_t)(N_NODES + 1) * 4);
    int*   col     = (int*)alloc((size_t)N_EDGES * 4);
    int*   gstart  = (int*)alloc((size_t)(NGRAPH + 1) * 4);
    int*   bsum    = (int*)alloc((size_t)SCB * 4);
    int*   boff    = (int*)alloc((size_t)SCB * 4);
    float* es      = (float*)alloc((size_t)N_NODES * HEADS * 4);
    float* edv     = (float*)alloc((size_t)N_NODES * HEADS * 4);
    bf16*  hA      = (bf16*)alloc((size_t)MPAD * HID * 2);
    bf16*  hB      = (bf16*)alloc((size_t)MPAD * HID * 2);
    unsigned char* x8  = (unsigned char*)alloc((size_t)N_NODES * DIN);
    unsigned char* hA8 = (unsigned char*)alloc((size_t)MPAD * HID);
    // union: acat0 (MPAD*128 bf16), acat1 (MPAD*256 bf16 = 512B/row), xw8 (MPAD*512 fp8)
    void*  u       = alloc((size_t)MPAD * 512);
    bf16*  acat0   = (bf16*)u;
    bf16*  acat1   = (bf16*)u;
    unsigned char* xw8 = (unsigned char*)u;
    // bf16 transposed weights
    bf16*  s0t     = (bf16*)alloc((size_t)128 * 128 * 2);
    bf16*  s1t     = (bf16*)alloc((size_t)128 * 256 * 2);
    bf16*  g0t     = (bf16*)alloc((size_t)512 * 128 * 2);
    bf16*  g1t     = (bf16*)alloc((size_t)512 * 128 * 2);
    bf16*  idpt    = (bf16*)alloc((size_t)3 * 128 * 128 * 2);

    hipMemsetAsync(zb, 0, (size_t)(2 * N_NODES + NGRAPH * HID) * 4, stream);

    // mega-prep: weights, x->fp8, degree count, graph bounds
    k_prep<<<(PREP_T + 255) / 256, 256, 0, stream>>>(
        s0_Wl, s0_Wr, s1_Wl, s1_Wr, g0_W, g1_W, idp_W, x, ei, batch,
        s0t, s1t, g0t, g1t, idpt, x8, deg, gstart);
    k_scan1<<<NSB, SCB, 0, stream>>>(deg, row_off, bsum);
    k_scan2<<<1, SCB, 0, stream>>>(bsum, boff);
    k_scan3<<<(N_NODES + 255) / 256, 256, 0, stream>>>(row_off, boff);
    k_fill<<<(N_EDGES + 255) / 256, 256, 0, stream>>>(ei, row_off, cursor, col);

    const int MB = (N_NODES + 63) / 64;   // 782 row-blocks

    // SAGE 0 (gemm also writes fp8 shadow hA8 for SAGE1's gathers)
    k_sage_agg0<<<N_NODES / 4, 256, 0, stream>>>(x8, x, row_off, col, acat0);
    k_gemm<128, 8, 5><<<dim3(MB, 1), 256, 0, stream>>>(
        acat0, s0t, hA, hA8, N_NODES, HID,
        s0_b, bn_g + 0 * HID, bn_b + 0 * HID, bn_m + 0 * HID, bn_v + 0 * HID, pre_a + 0 * HID,
        nullptr, nullptr, nullptr, nullptr);

    // SAGE 1
    k_sage_agg1<<<N_NODES / 4, 256, 0, stream>>>(hA8, hA, row_off, col, acat1);
    k_gemm<256, 8, 1><<<dim3(MB, 1), 256, 0, stream>>>(
        acat1, s1t, hB, nullptr, N_NODES, HID,
        s1_b, bn_g + 1 * HID, bn_b + 1 * HID, bn_m + 1 * HID, bn_v + 1 * HID, pre_a + 1 * HID,
        nullptr, nullptr, nullptr, nullptr);

    // GAT 0 (gemm stores fp8 xw + fuses score computation)
    k_gemm<128, 8, 4><<<dim3(MB, 4), 256, 0, stream>>>(
        hB, g0t, xw8, nullptr, N_NODES, HEADS * HID,
        nullptr, nullptr, nullptr, nullptr, nullptr, nullptr,
        g0_as, g0_ad, es, edv);
    k_gat_agg<<<N_NODES / 4, 256, 0, stream>>>(
        xw8, es, edv, row_off, col, g0_bias,
        bn_g + 2 * HID, bn_b + 2 * HID, bn_m + 2 * HID, bn_v + 2 * HID, pre_a + 2 * HID, hA);

    // GAT 1
    k_gemm<128, 8, 4><<<dim3(MB, 4), 256, 0, stream>>>(
        hA, g1t, xw8, nullptr, N_NODES, HEADS * HID,
        nullptr, nullptr, nullptr, nullptr, nullptr, nullptr,
        g1_as, g1_ad, es, edv);
    k_gat_agg<<<N_NODES / 4, 256, 0, stream>>>(
        xw8, es, edv, row_off, col, g1_bias,
        bn_g + 3 * HID, bn_b + 3 * HID, bn_m + 3 * HID, bn_v + 3 * HID, pre_a + 3 * HID, hB);

    // IDP MLP (3 layers fused) + mean-pool accumulation (no hA round-trip)
    k_mlp3<<<MB, 256, 0, stream>>>(
        hB, idpt + 0 * 16384, idpt + 1 * 16384, idpt + 2 * 16384,
        idp_b + 0 * HID, idp_a + 0 * HID,
        idp_b + 1 * HID, idp_a + 1 * HID,
        idp_b + 2 * HID, batch, pool, N_NODES);

    // classifier
    k_cls<<<1, NGRAPH * NCLS, 0, stream>>>(pool, gstart, cls_W, cls_b, out);
}